// Round 6
// baseline (245.087 us; speedup 1.0000x reference)
//
#include <hip/hip_runtime.h>

#define NNODE 10000
#define NEDGE 160000

using frag8 = __attribute__((ext_vector_type(8))) short;
using f32x4 = __attribute__((ext_vector_type(4))) float;

__device__ __forceinline__ unsigned short f2bf(float f) {
    union { float f; unsigned u; } v; v.f = f;
    unsigned r = (v.u + 0x7fffu + ((v.u >> 16) & 1u)) >> 16;
    return (unsigned short)r;
}
__device__ __forceinline__ float bf2f(unsigned short s) {
    union { unsigned u; float f; } v; v.u = ((unsigned)s) << 16; return v.f;
}

// ---------------- scan ----------------
__global__ __launch_bounds__(1024) void k_scan(const int* __restrict__ deg,
                                               int* __restrict__ rs,
                                               int* __restrict__ cur, int n, int total) {
    const int tid = threadIdx.x;
    const int CH = 10;
    const int base = tid * CH;
    int vals[CH];
    int tsum = 0;
#pragma unroll
    for (int j = 0; j < CH; j++) {
        int v = (base + j < n) ? deg[base + j] : 0;
        vals[j] = v; tsum += v;
    }
    const int lane = tid & 63, wid = tid >> 6;
    int x = tsum;
#pragma unroll
    for (int d = 1; d < 64; d <<= 1) {
        int y = __shfl_up(x, d, 64);
        if (lane >= d) x += y;
    }
    __shared__ int wt[16];
    if (lane == 63) wt[wid] = x;
    __syncthreads();
    if (tid == 0) {
        int c = 0;
#pragma unroll
        for (int k = 0; k < 16; k++) { int t = wt[k]; wt[k] = c; c += t; }
    }
    __syncthreads();
    int run = wt[wid] + x - tsum;
#pragma unroll
    for (int j = 0; j < CH; j++) {
        if (base + j < n) { rs[base + j] = run; cur[base + j] = run; }
        run += vals[j];
    }
    if (tid == 0) rs[n] = total;
}

__global__ void k_fill(const int* __restrict__ src, const int* __restrict__ dst,
                       int E, int* __restrict__ cur, int* __restrict__ csr) {
    int e = blockIdx.x * 256 + threadIdx.x;
    if (e < E) {
        int p = atomicAdd(&cur[dst[e]], 1);
        csr[p] = src[e];
    }
}

// ---------------- fused prep: x-cast + weight transposes + scale/shift + edge count ----------------
// bt1 = [w_l1;w_r1]^T  (512 out x 1024 K), bt2 likewise.
// bt3 = [w_l3 | w_r3]^T as (512 out x 512 K): rows 0..255 = w_l3 cols, rows 256..511 = w_r3 cols.
__global__ __launch_bounds__(256) void k_prep(
    const float* __restrict__ x, unsigned short* __restrict__ xb,
    const float* __restrict__ wl1, const float* __restrict__ wr1,
    const float* __restrict__ wl2, const float* __restrict__ wr2,
    const float* __restrict__ wl3, const float* __restrict__ wr3,
    unsigned short* __restrict__ bt1, unsigned short* __restrict__ bt2,
    unsigned short* __restrict__ bt3,
    const float* __restrict__ b1, const float* __restrict__ g1, const float* __restrict__ be1,
    const float* __restrict__ m1, const float* __restrict__ v1,
    const float* __restrict__ b2, const float* __restrict__ g2, const float* __restrict__ be2,
    const float* __restrict__ m2, const float* __restrict__ v2,
    const float* __restrict__ b3,
    float* __restrict__ sc1, float* __restrict__ sh1,
    float* __restrict__ sc2, float* __restrict__ sh2,
    float* __restrict__ sc3, float* __restrict__ sh3,
    const int* __restrict__ dstI, int* __restrict__ deg) {
    const int b = blockIdx.x, tid = threadIdx.x;
    if (b < 5000) {                       // x cast
        int i = b * 256 + tid;
        float4 f = ((const float4*)x)[i];
        ushort4 o;
        o.x = f2bf(f.x); o.y = f2bf(f.y); o.z = f2bf(f.z); o.w = f2bf(f.w);
        ((ushort4*)xb)[i] = o;
        return;
    }
    if (b >= 6281) {                      // edge degree count
        int e = (b - 6281) * 256 + tid;
        if (e < NEDGE) atomicAdd(&deg[dstI[e]], 1);
        return;
    }
    if (b == 6280) {                      // scale/shift
        for (int t = tid; t < 512; t += 256) {
            float s1 = g1[t] * rsqrtf(v1[t] + 1e-5f);
            sc1[t] = s1; sh1[t] = (b1[t] - m1[t]) * s1 + be1[t];
            float s2 = g2[t] * rsqrtf(v2[t] + 1e-5f);
            sc2[t] = s2; sh2[t] = (b2[t] - m2[t]) * s2 + be2[t];
            sc3[t] = 1.0f; sh3[t] = (t < 256) ? 0.0f : b3[t - 256];
        }
        return;
    }
    __shared__ float t[32][33];
    int tj = b - 5000;
    const float* srcp; unsigned short* dstp; int C, koff, ntilesN, rowoff, dstride;
    if (tj < 1024) {
        int job = tj >> 8; int tile = tj & 255; C = 512; ntilesN = 16;
        srcp = (job == 0) ? wl1 : (job == 1) ? wr1 : (job == 2) ? wl2 : wr2;
        dstp = (job < 2) ? bt1 : bt2; koff = (job & 1) * 512; rowoff = 0; dstride = 1024;
        tj = tile;
    } else {
        int jj = tj - 1024; int job = jj >> 7; int tile = jj & 127; C = 256; ntilesN = 8;
        srcp = (job == 0) ? wl3 : wr3; dstp = bt3; koff = 0; rowoff = job * 256; dstride = 512;
        tj = tile;
    }
    int k0 = (tj / ntilesN) * 32, c0 = (tj % ntilesN) * 32;
    int tx = tid & 31, ty = tid >> 5;
#pragma unroll
    for (int q = 0; q < 4; q++)
        t[ty + 8 * q][tx] = srcp[(long)(k0 + ty + 8 * q) * C + c0 + tx];
    __syncthreads();
#pragma unroll
    for (int q = 0; q < 4; q++)
        dstp[(long)(rowoff + c0 + ty + 8 * q) * dstride + koff + k0 + tx] = f2bf(t[tx][ty + 8 * q]);
}

// ---------------- aggregation: 4 waves per node (4x memory-level parallelism), uint4 loads ----------------
// Wave wv takes edges s+wv, s+wv+4, ... ; 4-deep unroll -> up to 16 row-loads in flight per node.
// Partial sums combined via 6KB LDS tree-reduce.
__global__ __launch_bounds__(256) void k_agg(const unsigned short* __restrict__ S,
                                             const int* __restrict__ rs, const int* __restrict__ csr,
                                             unsigned short* __restrict__ outb) {
    const int n = blockIdx.x;
    const int wv = threadIdx.x >> 6, lane = threadIdx.x & 63;
    const int c = lane * 8;
    const int s = rs[n], e = rs[n + 1];
    float a[8];
#pragma unroll
    for (int k = 0; k < 8; k++) a[k] = 0.f;

#define ACC(u) \
        a[0] += bf2f((unsigned short)((u).x & 0xffffu)); a[1] += bf2f((unsigned short)((u).x >> 16)); \
        a[2] += bf2f((unsigned short)((u).y & 0xffffu)); a[3] += bf2f((unsigned short)((u).y >> 16)); \
        a[4] += bf2f((unsigned short)((u).z & 0xffffu)); a[5] += bf2f((unsigned short)((u).z >> 16)); \
        a[6] += bf2f((unsigned short)((u).w & 0xffffu)); a[7] += bf2f((unsigned short)((u).w >> 16));

    int i = s + wv;
    for (; i + 12 < e; i += 16) {          // 4 strided edges for this wave, loads independent
        int r0 = csr[i], r1 = csr[i + 4], r2 = csr[i + 8], r3 = csr[i + 12];
        uint4 u0 = *(const uint4*)(S + (long)r0 * 512 + c);
        uint4 u1 = *(const uint4*)(S + (long)r1 * 512 + c);
        uint4 u2 = *(const uint4*)(S + (long)r2 * 512 + c);
        uint4 u3 = *(const uint4*)(S + (long)r3 * 512 + c);
        ACC(u0) ACC(u1) ACC(u2) ACC(u3)
    }
    for (; i < e; i += 4) {
        uint4 u = *(const uint4*)(S + (long)csr[i] * 512 + c);
        ACC(u)
    }
#undef ACC

    __shared__ float red[3][512];
    if (wv > 0) {
#pragma unroll
        for (int k = 0; k < 8; k++) red[wv - 1][c + k] = a[k];
    }
    __syncthreads();
    if (wv == 0) {
#pragma unroll
        for (int k = 0; k < 8; k++) a[k] += red[0][c + k] + red[1][c + k] + red[2][c + k];
        const int cnt = e - s;
        const float inv = 1.f / (float)(cnt > 1 ? cnt : 1);
        uint4 o;
        o.x = (unsigned)f2bf(a[0] * inv) | ((unsigned)f2bf(a[1] * inv) << 16);
        o.y = (unsigned)f2bf(a[2] * inv) | ((unsigned)f2bf(a[3] * inv) << 16);
        o.z = (unsigned)f2bf(a[4] * inv) | ((unsigned)f2bf(a[5] * inv) << 16);
        o.w = (unsigned)f2bf(a[6] * inv) | ((unsigned)f2bf(a[7] * inv) << 16);
        *(uint4*)(outb + (long)n * 512 + c) = o;
    }
}

// ---------------- layer-3 final: out[n] = mean(P[src]) + Q[n], fp32 out; 4 waves per node ----------------
// PQ is [N x 512] bf16: cols 0..255 = P = h2@w_l3, cols 256..511 = Q = h2@w_r3 + b3.
__global__ __launch_bounds__(256) void k_agg_fuse(const unsigned short* __restrict__ PQ,
                                                  const int* __restrict__ rs, const int* __restrict__ csr,
                                                  float* __restrict__ out) {
    const int n = blockIdx.x;
    const int wv = threadIdx.x >> 6, lane = threadIdx.x & 63;
    const int c = lane * 4;
    const int s = rs[n], e = rs[n + 1];
    float a0 = 0.f, a1 = 0.f, a2 = 0.f, a3 = 0.f;

#define ACC(u) \
        a0 += bf2f((unsigned short)((u).x & 0xffffu)); a1 += bf2f((unsigned short)((u).x >> 16)); \
        a2 += bf2f((unsigned short)((u).y & 0xffffu)); a3 += bf2f((unsigned short)((u).y >> 16));

    int i = s + wv;
    for (; i + 12 < e; i += 16) {
        int r0 = csr[i], r1 = csr[i + 4], r2 = csr[i + 8], r3 = csr[i + 12];
        uint2 u0 = *(const uint2*)(PQ + (long)r0 * 512 + c);
        uint2 u1 = *(const uint2*)(PQ + (long)r1 * 512 + c);
        uint2 u2 = *(const uint2*)(PQ + (long)r2 * 512 + c);
        uint2 u3 = *(const uint2*)(PQ + (long)r3 * 512 + c);
        ACC(u0) ACC(u1) ACC(u2) ACC(u3)
    }
    for (; i < e; i += 4) {
        uint2 u = *(const uint2*)(PQ + (long)csr[i] * 512 + c);
        ACC(u)
    }
#undef ACC

    __shared__ float red[3][256];
    if (wv > 0) {
        red[wv - 1][c + 0] = a0; red[wv - 1][c + 1] = a1;
        red[wv - 1][c + 2] = a2; red[wv - 1][c + 3] = a3;
    }
    __syncthreads();
    if (wv == 0) {
        uint2 q = *(const uint2*)(PQ + (long)n * 512 + 256 + c);
        a0 += red[0][c + 0] + red[1][c + 0] + red[2][c + 0];
        a1 += red[0][c + 1] + red[1][c + 1] + red[2][c + 1];
        a2 += red[0][c + 2] + red[1][c + 2] + red[2][c + 2];
        a3 += red[0][c + 3] + red[1][c + 3] + red[2][c + 3];
        const int cnt = e - s;
        const float inv = 1.f / (float)(cnt > 1 ? cnt : 1);
        float4 o;
        o.x = a0 * inv + bf2f((unsigned short)(q.x & 0xffffu));
        o.y = a1 * inv + bf2f((unsigned short)(q.x >> 16));
        o.z = a2 * inv + bf2f((unsigned short)(q.y & 0xffffu));
        o.w = a3 * inv + bf2f((unsigned short)(q.y >> 16));
        *(float4*)&out[(long)n * 256 + c] = o;
    }
}

// ---------------- GEMM: 64x128 tile, 2x4 frags/wave, LDS dbuf, XCD swizzle, 3 blocks/CU ----------------
// 157 M-tiles x 4 N-tiles = 628 blocks; at 3 blocks/CU (144KB LDS) all are co-resident in ONE round.
// SPLIT: C = [Agg|Self][M x 1024] @ Bt[NOUT x 1024]^T (16 K-steps).
// !SPLIT: C = Self[M x 512] @ Bt[NOUT x 512]^T (8 K-steps).
// Operands SWAPPED at MFMA (mfma(bf, af)): lane holds row = ...+fr, cols = ...+fq*4+{0..3}
// -> packed 8B stores, float4 sc/sh loads.
// MODE 0: relu(dot*sc+sh) -> bf16 ; MODE 2: dot*sc+sh -> bf16 (no relu). Stride NOUT.
template <int MODE, int NOUT, bool SPLIT>
__global__ __launch_bounds__(256, 3) void k_gemm(const unsigned short* __restrict__ Agg,
                                                 const unsigned short* __restrict__ Self,
                                                 const unsigned short* __restrict__ Bt,
                                                 const float* __restrict__ sc, const float* __restrict__ sh,
                                                 unsigned short* __restrict__ hout, int M) {
    constexpr int NT = NOUT / 128;          // n-tiles: 4 or 2
    constexpr int QSH = (NT == 4) ? 5 : 4;  // 3 + log2(NT)
    constexpr int KSTEPS = SPLIT ? 16 : 8;
    constexpr int BSTR = SPLIT ? 1024 : 512;
    const int b = blockIdx.x;
    const int X = b & 7;
    const int q = (b >> 3) & (NT - 1);
    const int g = b >> QSH;
    const int m0 = (g * 8 + X) * 64;        // 64-row tiles
    if (m0 >= M) return;
    const int n0 = q * 128;

    __shared__ __align__(16) short As[2][64 * 64];    // 16 KB
    __shared__ __align__(16) short Bs[2][128 * 64];   // 32 KB
    const int tid = threadIdx.x;
    const int w = tid >> 6, lane = tid & 63;
    const int wm = (w >> 1) * 32, wn = (w & 1) * 64;  // wave tile 32x64
    const int fr = lane & 15, fq = lane >> 4, sw = fr & 7;
    const int srow = w * 8 + (lane >> 3);                 // 0..31 (+chunk*32)
    const int scol = (((lane & 7) ^ (lane >> 3)) * 8);    // XOR-swizzled source col (shorts)
    const int ldsOff = w * 8 * 64;

    f32x4 acc[2][4];
#pragma unroll
    for (int i = 0; i < 2; i++)
#pragma unroll
        for (int j = 0; j < 4; j++)
#pragma unroll
            for (int r = 0; r < 4; r++) acc[i][j][r] = 0.f;

    auto issue = [&](int t, int buf) {
        const short* abase;
        int kk;
        if constexpr (SPLIT) {
            abase = (const short*)((t < 8) ? Agg : Self);
            kk = (t & 7) * 64;
        } else {
            abase = (const short*)Self;
            kk = t * 64;
        }
        const int k0 = t * 64;
#pragma unroll
        for (int cch = 0; cch < 2; cch++) {   // A: 64 rows = 2 chunks of 32
            __builtin_amdgcn_global_load_lds(
                (const __attribute__((address_space(1))) void*)(abase + (long)(m0 + cch * 32 + srow) * 512 + kk + scol),
                (__attribute__((address_space(3))) void*)(&As[buf][ldsOff + cch * 32 * 64]), 16, 0, 0);
        }
#pragma unroll
        for (int cch = 0; cch < 4; cch++) {   // B: 128 rows = 4 chunks of 32
            __builtin_amdgcn_global_load_lds(
                (const __attribute__((address_space(1))) void*)((const short*)Bt + (long)(n0 + cch * 32 + srow) * BSTR + k0 + scol),
                (__attribute__((address_space(3))) void*)(&Bs[buf][ldsOff + cch * 32 * 64]), 16, 0, 0);
        }
    };

    issue(0, 0);
#pragma unroll
    for (int t = 0; t < KSTEPS; t++) {
        const int cur = t & 1;
        __syncthreads();                  // drains DMA(t); all waves' reads of this buf (from t-2) are done
        if (t < KSTEPS - 1) issue(t + 1, cur ^ 1);
#pragma unroll
        for (int ks = 0; ks < 2; ks++) {
            frag8 af[2], bf[4];
#pragma unroll
            for (int i = 0; i < 2; i++)
                af[i] = *(const frag8*)(&As[cur][(wm + i * 16 + fr) * 64 + (((ks * 4 + fq) ^ sw) * 8)]);
#pragma unroll
            for (int j = 0; j < 4; j++)
                bf[j] = *(const frag8*)(&Bs[cur][(wn + j * 16 + fr) * 64 + (((ks * 4 + fq) ^ sw) * 8)]);
#pragma unroll
            for (int i = 0; i < 2; i++)
#pragma unroll
                for (int j = 0; j < 4; j++)
                    acc[i][j] = __builtin_amdgcn_mfma_f32_16x16x32_bf16(bf[j], af[i], acc[i][j], 0, 0, 0);
        }
    }

    // Epilogue: lane holds row = m0+wm+i*16+fr, cols = n0+wn+j*16+fq*4+{0..3}
#pragma unroll
    for (int j = 0; j < 4; j++) {
        const int colb = n0 + wn + j * 16 + fq * 4;
        const float4 s4 = *(const float4*)&sc[colb];
        const float4 h4 = *(const float4*)&sh[colb];
#pragma unroll
        for (int i = 0; i < 2; i++) {
            const int row = m0 + wm + i * 16 + fr;
            if (row < M) {
                float y0 = acc[i][j][0] * s4.x + h4.x;
                float y1 = acc[i][j][1] * s4.y + h4.y;
                float y2 = acc[i][j][2] * s4.z + h4.z;
                float y3 = acc[i][j][3] * s4.w + h4.w;
                if constexpr (MODE == 0) {
                    y0 = fmaxf(y0, 0.f); y1 = fmaxf(y1, 0.f);
                    y2 = fmaxf(y2, 0.f); y3 = fmaxf(y3, 0.f);
                }
                uint2 o;
                o.x = (unsigned)f2bf(y0) | ((unsigned)f2bf(y1) << 16);
                o.y = (unsigned)f2bf(y2) | ((unsigned)f2bf(y3) << 16);
                *(uint2*)&hout[(long)row * NOUT + colb] = o;
            }
        }
    }
}

extern "C" void kernel_launch(void* const* d_in, const int* in_sizes, int n_in,
                              void* d_out, int out_size, void* d_ws, size_t ws_size,
                              hipStream_t stream) {
    const float* x    = (const float*)d_in[0];
    const int*   ei   = (const int*)d_in[1];
    const float* w_l1 = (const float*)d_in[2];
    const float* b1   = (const float*)d_in[3];
    const float* w_r1 = (const float*)d_in[4];
    const float* g1   = (const float*)d_in[5];
    const float* be1  = (const float*)d_in[6];
    const float* m1   = (const float*)d_in[7];
    const float* v1   = (const float*)d_in[8];
    const float* w_l2 = (const float*)d_in[9];
    const float* b2   = (const float*)d_in[10];
    const float* w_r2 = (const float*)d_in[11];
    const float* g2   = (const float*)d_in[12];
    const float* be2  = (const float*)d_in[13];
    const float* m2   = (const float*)d_in[14];
    const float* v2   = (const float*)d_in[15];
    const float* w_l3 = (const float*)d_in[16];
    const float* b3   = (const float*)d_in[17];
    const float* w_r3 = (const float*)d_in[18];
    float* out = (float*)d_out;

    const int N = NNODE, E = NEDGE;
    const int* srcI = ei;
    const int* dstI = ei + E;

    char* w = (char*)d_ws;
    auto alloc = [&](size_t bytes) { void* p = (void*)w; w += (bytes + 255) & ~(size_t)255; return p; };
    int* deg = (int*)alloc((size_t)N * 4);
    int* rs  = (int*)alloc((size_t)(N + 1) * 4);
    int* cur = (int*)alloc((size_t)N * 4);
    int* csr = (int*)alloc((size_t)E * 4);
    unsigned short* xb   = (unsigned short*)alloc((size_t)N * 512 * 2);
    unsigned short* bt1  = (unsigned short*)alloc((size_t)512 * 1024 * 2);
    unsigned short* bt2  = (unsigned short*)alloc((size_t)512 * 1024 * 2);
    unsigned short* bt3  = (unsigned short*)alloc((size_t)512 * 512 * 2);
    float* sc1 = (float*)alloc(512 * 4); float* sh1 = (float*)alloc(512 * 4);
    float* sc2 = (float*)alloc(512 * 4); float* sh2 = (float*)alloc(512 * 4);
    float* sc3 = (float*)alloc(512 * 4); float* sh3 = (float*)alloc(512 * 4);
    unsigned short* agg_a = (unsigned short*)alloc((size_t)N * 512 * 2);  // also reused as PQ for layer 3
    unsigned short* h1    = (unsigned short*)alloc((size_t)N * 512 * 2);
    unsigned short* h2    = (unsigned short*)alloc((size_t)N * 512 * 2);
    (void)alloc(256 * 1024);  // DMA over-read slack for last M-tile

    hipMemsetAsync(deg, 0, (size_t)N * 4, stream);
    k_prep<<<6906, 256, 0, stream>>>(x, xb, w_l1, w_r1, w_l2, w_r2, w_l3, w_r3,
                                     bt1, bt2, bt3,
                                     b1, g1, be1, m1, v1, b2, g2, be2, m2, v2, b3,
                                     sc1, sh1, sc2, sh2, sc3, sh3, dstI, deg);
    k_scan<<<1, 1024, 0, stream>>>(deg, rs, cur, N, E);
    k_fill<<<(E + 255) / 256, 256, 0, stream>>>(srcI, dstI, E, cur, csr);

    // 64-row tiles: ceil(157/8)=20 strip-groups * 8 XCD * 4 n-tiles = 640 blocks (628 active)
    // Layer 1
    k_agg<<<N, 256, 0, stream>>>(xb, rs, csr, agg_a);
    k_gemm<0, 512, true><<<640, 256, 0, stream>>>(agg_a, xb, bt1, sc1, sh1, h1, N);
    // Layer 2
    k_agg<<<N, 256, 0, stream>>>(h1, rs, csr, agg_a);
    k_gemm<0, 512, true><<<640, 256, 0, stream>>>(agg_a, h1, bt2, sc2, sh2, h2, N);
    // Layer 3: project first (PQ = [h2@w_l3 | h2@w_r3+b3]), then aggregate only the 256-wide P half
    k_gemm<2, 512, false><<<640, 256, 0, stream>>>(h2, h2, bt3, sc3, sh3, agg_a, N);
    k_agg_fuse<<<N, 256, 0, stream>>>(agg_a, rs, csr, out);
}

// Round 7
// 222.998 us; speedup vs baseline: 1.0991x; 1.0991x over previous
//
#include <hip/hip_runtime.h>

#define NNODE 10000
#define NEDGE 160000
#define SLOTS 128

using frag8 = __attribute__((ext_vector_type(8))) short;
using f32x4 = __attribute__((ext_vector_type(4))) float;

__device__ __forceinline__ unsigned short f2bf(float f) {
    union { float f; unsigned u; } v; v.f = f;
    unsigned r = (v.u + 0x7fffu + ((v.u >> 16) & 1u)) >> 16;
    return (unsigned short)r;
}
__device__ __forceinline__ float bf2f(unsigned short s) {
    union { unsigned u; float f; } v; v.u = ((unsigned)s) << 16; return v.f;
}

// ---------------- padded-CSR fill: slot = atomicAdd(cnt[dst]); csrp[dst*SLOTS+slot] = src ----------------
__global__ void k_fillp(const int* __restrict__ src, const int* __restrict__ dst,
                        int E, int* __restrict__ cnt, int* __restrict__ csrp) {
    int e = blockIdx.x * 256 + threadIdx.x;
    if (e < E) {
        int d = dst[e];
        int p = atomicAdd(&cnt[d], 1);
        csrp[(long)d * SLOTS + p] = src[e];
    }
}

// ---------------- fused prep: x-cast + weight transposes + scale/shift ----------------
// bt1 = [w_l1;w_r1]^T  (512 out x 1024 K), bt2 likewise.
// bt3 = [w_l3 | w_r3]^T as (512 out x 512 K): rows 0..255 = w_l3 cols, rows 256..511 = w_r3 cols.
__global__ __launch_bounds__(256) void k_prep(
    const float* __restrict__ x, unsigned short* __restrict__ xb,
    const float* __restrict__ wl1, const float* __restrict__ wr1,
    const float* __restrict__ wl2, const float* __restrict__ wr2,
    const float* __restrict__ wl3, const float* __restrict__ wr3,
    unsigned short* __restrict__ bt1, unsigned short* __restrict__ bt2,
    unsigned short* __restrict__ bt3,
    const float* __restrict__ b1, const float* __restrict__ g1, const float* __restrict__ be1,
    const float* __restrict__ m1, const float* __restrict__ v1,
    const float* __restrict__ b2, const float* __restrict__ g2, const float* __restrict__ be2,
    const float* __restrict__ m2, const float* __restrict__ v2,
    const float* __restrict__ b3,
    float* __restrict__ sc1, float* __restrict__ sh1,
    float* __restrict__ sc2, float* __restrict__ sh2,
    float* __restrict__ sc3, float* __restrict__ sh3) {
    const int b = blockIdx.x, tid = threadIdx.x;
    if (b < 5000) {                       // x cast
        int i = b * 256 + tid;
        float4 f = ((const float4*)x)[i];
        ushort4 o;
        o.x = f2bf(f.x); o.y = f2bf(f.y); o.z = f2bf(f.z); o.w = f2bf(f.w);
        ((ushort4*)xb)[i] = o;
        return;
    }
    if (b == 6280) {                      // scale/shift
        for (int t = tid; t < 512; t += 256) {
            float s1 = g1[t] * rsqrtf(v1[t] + 1e-5f);
            sc1[t] = s1; sh1[t] = (b1[t] - m1[t]) * s1 + be1[t];
            float s2 = g2[t] * rsqrtf(v2[t] + 1e-5f);
            sc2[t] = s2; sh2[t] = (b2[t] - m2[t]) * s2 + be2[t];
            sc3[t] = 1.0f; sh3[t] = (t < 256) ? 0.0f : b3[t - 256];
        }
        return;
    }
    __shared__ float t[32][33];
    int tj = b - 5000;
    const float* srcp; unsigned short* dstp; int C, koff, ntilesN, rowoff, dstride;
    if (tj < 1024) {
        int job = tj >> 8; int tile = tj & 255; C = 512; ntilesN = 16;
        srcp = (job == 0) ? wl1 : (job == 1) ? wr1 : (job == 2) ? wl2 : wr2;
        dstp = (job < 2) ? bt1 : bt2; koff = (job & 1) * 512; rowoff = 0; dstride = 1024;
        tj = tile;
    } else {
        int jj = tj - 1024; int job = jj >> 7; int tile = jj & 127; C = 256; ntilesN = 8;
        srcp = (job == 0) ? wl3 : wr3; dstp = bt3; koff = 0; rowoff = job * 256; dstride = 512;
        tj = tile;
    }
    int k0 = (tj / ntilesN) * 32, c0 = (tj % ntilesN) * 32;
    int tx = tid & 31, ty = tid >> 5;
#pragma unroll
    for (int q = 0; q < 4; q++)
        t[ty + 8 * q][tx] = srcp[(long)(k0 + ty + 8 * q) * C + c0 + tx];
    __syncthreads();
#pragma unroll
    for (int q = 0; q < 4; q++)
        dstp[(long)(rowoff + c0 + ty + 8 * q) * dstride + koff + k0 + tx] = f2bf(t[tx][ty + 8 * q]);
}

// ---------------- aggregation: 1 wave/node, single pass, uint4 (16B/lane), padded CSR ----------------
__global__ __launch_bounds__(64) void k_agg(const unsigned short* __restrict__ S,
                                            const int* __restrict__ cnt, const int* __restrict__ csrp,
                                            unsigned short* __restrict__ outb) {
    const int n = blockIdx.x;
    const int c = threadIdx.x * 8;
    const int e = cnt[n];
    const int* __restrict__ lst = csrp + (long)n * SLOTS;
    float a[8];
#pragma unroll
    for (int k = 0; k < 8; k++) a[k] = 0.f;
    int i = 0;
    for (; i + 4 <= e; i += 4) {
        int r0 = lst[i], r1 = lst[i + 1], r2 = lst[i + 2], r3 = lst[i + 3];
        uint4 u0 = *(const uint4*)(S + (long)r0 * 512 + c);
        uint4 u1 = *(const uint4*)(S + (long)r1 * 512 + c);
        uint4 u2 = *(const uint4*)(S + (long)r2 * 512 + c);
        uint4 u3 = *(const uint4*)(S + (long)r3 * 512 + c);
#define ACC(u) \
        a[0] += bf2f((unsigned short)((u).x & 0xffffu)); a[1] += bf2f((unsigned short)((u).x >> 16)); \
        a[2] += bf2f((unsigned short)((u).y & 0xffffu)); a[3] += bf2f((unsigned short)((u).y >> 16)); \
        a[4] += bf2f((unsigned short)((u).z & 0xffffu)); a[5] += bf2f((unsigned short)((u).z >> 16)); \
        a[6] += bf2f((unsigned short)((u).w & 0xffffu)); a[7] += bf2f((unsigned short)((u).w >> 16));
        ACC(u0) ACC(u1) ACC(u2) ACC(u3)
    }
    for (; i < e; i++) {
        uint4 u = *(const uint4*)(S + (long)lst[i] * 512 + c);
        ACC(u)
    }
#undef ACC
    const float inv = 1.f / (float)(e > 1 ? e : 1);
    uint4 o;
    o.x = (unsigned)f2bf(a[0] * inv) | ((unsigned)f2bf(a[1] * inv) << 16);
    o.y = (unsigned)f2bf(a[2] * inv) | ((unsigned)f2bf(a[3] * inv) << 16);
    o.z = (unsigned)f2bf(a[4] * inv) | ((unsigned)f2bf(a[5] * inv) << 16);
    o.w = (unsigned)f2bf(a[6] * inv) | ((unsigned)f2bf(a[7] * inv) << 16);
    *(uint4*)(outb + (long)n * 512 + c) = o;
}

// ---------------- layer-3 final: out[n] = mean(P[src]) + Q[n], fp32 out; 1 wave/node ----------------
// PQ is [N x 512] bf16: cols 0..255 = P = h2@w_l3, cols 256..511 = Q = h2@w_r3 + b3.
__global__ __launch_bounds__(64) void k_agg_fuse(const unsigned short* __restrict__ PQ,
                                                 const int* __restrict__ cnt, const int* __restrict__ csrp,
                                                 float* __restrict__ out) {
    const int n = blockIdx.x;
    const int c = threadIdx.x * 4;
    const int e = cnt[n];
    const int* __restrict__ lst = csrp + (long)n * SLOTS;
    uint2 q = *(const uint2*)(PQ + (long)n * 512 + 256 + c);   // issue early
    float a0 = 0.f, a1 = 0.f, a2 = 0.f, a3 = 0.f;
    int i = 0;
    for (; i + 4 <= e; i += 4) {
        int r0 = lst[i], r1 = lst[i + 1], r2 = lst[i + 2], r3 = lst[i + 3];
        uint2 u0 = *(const uint2*)(PQ + (long)r0 * 512 + c);
        uint2 u1 = *(const uint2*)(PQ + (long)r1 * 512 + c);
        uint2 u2 = *(const uint2*)(PQ + (long)r2 * 512 + c);
        uint2 u3 = *(const uint2*)(PQ + (long)r3 * 512 + c);
#define ACC(u) \
        a0 += bf2f((unsigned short)((u).x & 0xffffu)); a1 += bf2f((unsigned short)((u).x >> 16)); \
        a2 += bf2f((unsigned short)((u).y & 0xffffu)); a3 += bf2f((unsigned short)((u).y >> 16));
        ACC(u0) ACC(u1) ACC(u2) ACC(u3)
    }
    for (; i < e; i++) {
        uint2 u = *(const uint2*)(PQ + (long)lst[i] * 512 + c);
        ACC(u)
    }
#undef ACC
    const float inv = 1.f / (float)(e > 1 ? e : 1);
    float4 o;
    o.x = a0 * inv + bf2f((unsigned short)(q.x & 0xffffu));
    o.y = a1 * inv + bf2f((unsigned short)(q.x >> 16));
    o.z = a2 * inv + bf2f((unsigned short)(q.y & 0xffffu));
    o.w = a3 * inv + bf2f((unsigned short)(q.y >> 16));
    *(float4*)&out[(long)n * 256 + c] = o;
}

// ---------------- GEMM: 64x128 tile, 2x4 frags/wave, LDS dbuf, XCD swizzle, 3 blocks/CU ----------------
// 157 M-tiles x 4 N-tiles = 628 blocks; at 3 blocks/CU (144KB LDS) all are co-resident in ONE round.
// SPLIT: C = [Agg|Self][M x 1024] @ Bt[NOUT x 1024]^T (16 K-steps).
// !SPLIT: C = Self[M x 512] @ Bt[NOUT x 512]^T (8 K-steps).
// Operands SWAPPED at MFMA (mfma(bf, af)): lane holds row = ...+fr, cols = ...+fq*4+{0..3}
// -> packed 8B stores, float4 sc/sh loads.
// MODE 0: relu(dot*sc+sh) -> bf16 ; MODE 2: dot*sc+sh -> bf16 (no relu). Stride NOUT.
template <int MODE, int NOUT, bool SPLIT>
__global__ __launch_bounds__(256, 3) void k_gemm(const unsigned short* __restrict__ Agg,
                                                 const unsigned short* __restrict__ Self,
                                                 const unsigned short* __restrict__ Bt,
                                                 const float* __restrict__ sc, const float* __restrict__ sh,
                                                 unsigned short* __restrict__ hout, int M) {
    constexpr int NT = NOUT / 128;          // n-tiles: 4 or 2
    constexpr int QSH = (NT == 4) ? 5 : 4;  // 3 + log2(NT)
    constexpr int KSTEPS = SPLIT ? 16 : 8;
    constexpr int BSTR = SPLIT ? 1024 : 512;
    const int b = blockIdx.x;
    const int X = b & 7;
    const int q = (b >> 3) & (NT - 1);
    const int g = b >> QSH;
    const int m0 = (g * 8 + X) * 64;        // 64-row tiles
    if (m0 >= M) return;
    const int n0 = q * 128;

    __shared__ __align__(16) short As[2][64 * 64];    // 16 KB
    __shared__ __align__(16) short Bs[2][128 * 64];   // 32 KB
    const int tid = threadIdx.x;
    const int w = tid >> 6, lane = tid & 63;
    const int wm = (w >> 1) * 32, wn = (w & 1) * 64;  // wave tile 32x64
    const int fr = lane & 15, fq = lane >> 4, sw = fr & 7;
    const int srow = w * 8 + (lane >> 3);                 // 0..31 (+chunk*32)
    const int scol = (((lane & 7) ^ (lane >> 3)) * 8);    // XOR-swizzled source col (shorts)
    const int ldsOff = w * 8 * 64;

    f32x4 acc[2][4];
#pragma unroll
    for (int i = 0; i < 2; i++)
#pragma unroll
        for (int j = 0; j < 4; j++)
#pragma unroll
            for (int r = 0; r < 4; r++) acc[i][j][r] = 0.f;

    auto issue = [&](int t, int buf) {
        const short* abase;
        int kk;
        if constexpr (SPLIT) {
            abase = (const short*)((t < 8) ? Agg : Self);
            kk = (t & 7) * 64;
        } else {
            abase = (const short*)Self;
            kk = t * 64;
        }
        const int k0 = t * 64;
#pragma unroll
        for (int cch = 0; cch < 2; cch++) {   // A: 64 rows = 2 chunks of 32
            __builtin_amdgcn_global_load_lds(
                (const __attribute__((address_space(1))) void*)(abase + (long)(m0 + cch * 32 + srow) * 512 + kk + scol),
                (__attribute__((address_space(3))) void*)(&As[buf][ldsOff + cch * 32 * 64]), 16, 0, 0);
        }
#pragma unroll
        for (int cch = 0; cch < 4; cch++) {   // B: 128 rows = 4 chunks of 32
            __builtin_amdgcn_global_load_lds(
                (const __attribute__((address_space(1))) void*)((const short*)Bt + (long)(n0 + cch * 32 + srow) * BSTR + k0 + scol),
                (__attribute__((address_space(3))) void*)(&Bs[buf][ldsOff + cch * 32 * 64]), 16, 0, 0);
        }
    };

    issue(0, 0);
#pragma unroll
    for (int t = 0; t < KSTEPS; t++) {
        const int cur = t & 1;
        __syncthreads();                  // drains DMA(t); all waves' reads of this buf (from t-2) are done
        if (t < KSTEPS - 1) issue(t + 1, cur ^ 1);
#pragma unroll
        for (int ks = 0; ks < 2; ks++) {
            frag8 af[2], bf[4];
#pragma unroll
            for (int i = 0; i < 2; i++)
                af[i] = *(const frag8*)(&As[cur][(wm + i * 16 + fr) * 64 + (((ks * 4 + fq) ^ sw) * 8)]);
#pragma unroll
            for (int j = 0; j < 4; j++)
                bf[j] = *(const frag8*)(&Bs[cur][(wn + j * 16 + fr) * 64 + (((ks * 4 + fq) ^ sw) * 8)]);
#pragma unroll
            for (int i = 0; i < 2; i++)
#pragma unroll
                for (int j = 0; j < 4; j++)
                    acc[i][j] = __builtin_amdgcn_mfma_f32_16x16x32_bf16(bf[j], af[i], acc[i][j], 0, 0, 0);
        }
    }

    // Epilogue: lane holds row = m0+wm+i*16+fr, cols = n0+wn+j*16+fq*4+{0..3}
#pragma unroll
    for (int j = 0; j < 4; j++) {
        const int colb = n0 + wn + j * 16 + fq * 4;
        const float4 s4 = *(const float4*)&sc[colb];
        const float4 h4 = *(const float4*)&sh[colb];
#pragma unroll
        for (int i = 0; i < 2; i++) {
            const int row = m0 + wm + i * 16 + fr;
            if (row < M) {
                float y0 = acc[i][j][0] * s4.x + h4.x;
                float y1 = acc[i][j][1] * s4.y + h4.y;
                float y2 = acc[i][j][2] * s4.z + h4.z;
                float y3 = acc[i][j][3] * s4.w + h4.w;
                if constexpr (MODE == 0) {
                    y0 = fmaxf(y0, 0.f); y1 = fmaxf(y1, 0.f);
                    y2 = fmaxf(y2, 0.f); y3 = fmaxf(y3, 0.f);
                }
                uint2 o;
                o.x = (unsigned)f2bf(y0) | ((unsigned)f2bf(y1) << 16);
                o.y = (unsigned)f2bf(y2) | ((unsigned)f2bf(y3) << 16);
                *(uint2*)&hout[(long)row * NOUT + colb] = o;
            }
        }
    }
}

extern "C" void kernel_launch(void* const* d_in, const int* in_sizes, int n_in,
                              void* d_out, int out_size, void* d_ws, size_t ws_size,
                              hipStream_t stream) {
    const float* x    = (const float*)d_in[0];
    const int*   ei   = (const int*)d_in[1];
    const float* w_l1 = (const float*)d_in[2];
    const float* b1   = (const float*)d_in[3];
    const float* w_r1 = (const float*)d_in[4];
    const float* g1   = (const float*)d_in[5];
    const float* be1  = (const float*)d_in[6];
    const float* m1   = (const float*)d_in[7];
    const float* v1   = (const float*)d_in[8];
    const float* w_l2 = (const float*)d_in[9];
    const float* b2   = (const float*)d_in[10];
    const float* w_r2 = (const float*)d_in[11];
    const float* g2   = (const float*)d_in[12];
    const float* be2  = (const float*)d_in[13];
    const float* m2   = (const float*)d_in[14];
    const float* v2   = (const float*)d_in[15];
    const float* w_l3 = (const float*)d_in[16];
    const float* b3   = (const float*)d_in[17];
    const float* w_r3 = (const float*)d_in[18];
    float* out = (float*)d_out;

    const int N = NNODE, E = NEDGE;
    const int* srcI = ei;
    const int* dstI = ei + E;

    char* w = (char*)d_ws;
    auto alloc = [&](size_t bytes) { void* p = (void*)w; w += (bytes + 255) & ~(size_t)255; return p; };
    int* cnt  = (int*)alloc((size_t)N * 4);
    int* csrp = (int*)alloc((size_t)N * SLOTS * 4);
    unsigned short* xb   = (unsigned short*)alloc((size_t)N * 512 * 2);
    unsigned short* bt1  = (unsigned short*)alloc((size_t)512 * 1024 * 2);
    unsigned short* bt2  = (unsigned short*)alloc((size_t)512 * 1024 * 2);
    unsigned short* bt3  = (unsigned short*)alloc((size_t)512 * 512 * 2);
    float* sc1 = (float*)alloc(512 * 4); float* sh1 = (float*)alloc(512 * 4);
    float* sc2 = (float*)alloc(512 * 4); float* sh2 = (float*)alloc(512 * 4);
    float* sc3 = (float*)alloc(512 * 4); float* sh3 = (float*)alloc(512 * 4);
    unsigned short* agg_a = (unsigned short*)alloc((size_t)N * 512 * 2);  // also reused as PQ for layer 3
    unsigned short* h1    = (unsigned short*)alloc((size_t)N * 512 * 2);
    unsigned short* h2    = (unsigned short*)alloc((size_t)N * 512 * 2);
    (void)alloc(256 * 1024);  // DMA over-read slack for last M-tile

    hipMemsetAsync(cnt, 0, (size_t)N * 4, stream);
    k_prep<<<6281, 256, 0, stream>>>(x, xb, w_l1, w_r1, w_l2, w_r2, w_l3, w_r3,
                                     bt1, bt2, bt3,
                                     b1, g1, be1, m1, v1, b2, g2, be2, m2, v2, b3,
                                     sc1, sh1, sc2, sh2, sc3, sh3);
    k_fillp<<<(E + 255) / 256, 256, 0, stream>>>(srcI, dstI, E, cnt, csrp);

    // 64-row tiles: ceil(157/8)=20 strip-groups * 8 XCD * 4 n-tiles = 640 blocks (628 active)
    // Layer 1
    k_agg<<<N, 64, 0, stream>>>(xb, cnt, csrp, agg_a);
    k_gemm<0, 512, true><<<640, 256, 0, stream>>>(agg_a, xb, bt1, sc1, sh1, h1, N);
    // Layer 2
    k_agg<<<N, 64, 0, stream>>>(h1, cnt, csrp, agg_a);
    k_gemm<0, 512, true><<<640, 256, 0, stream>>>(agg_a, h1, bt2, sc2, sh2, h2, N);
    // Layer 3: project first (PQ = [h2@w_l3 | h2@w_r3+b3]), then aggregate only the 256-wide P half
    k_gemm<2, 512, false><<<640, 256, 0, stream>>>(h2, h2, bt3, sc3, sh3, agg_a, N);
    k_agg_fuse<<<N, 64, 0, stream>>>(agg_a, cnt, csrp, out);
}